// Round 10
// baseline (223.551 us; speedup 1.0000x reference)
//
#include <hip/hip_runtime.h>
#include <hip/hip_bf16.h>

#define NF 22     // node features
#define H  32     // hidden dim
#define BSH 8     // 256 nodes per bucket
#define CAP 8192  // edge capacity per bucket (mean 4092 at E=1.6M, NB=391)
#define CHUNK 2048
// requires N <= 131072 (src fits 24 bits after <<8 shift; bucket count <= 512)

__device__ __forceinline__ float bflo(unsigned int v) { return __uint_as_float(v << 16); }
__device__ __forceinline__ float bfhi(unsigned int v) { return __uint_as_float(v & 0xffff0000u); }

// ---- init per-bucket cursors to fixed-capacity bases ----
__global__ void init_cur(int* __restrict__ cursor, int NB) {
    int i = blockIdx.x * blockDim.x + threadIdx.x;
    if (i < NB) cursor[i] = i * CAP;
}

// ---- bin edges by dst bucket; packed (src<<8)|(dst&255); dense reserved writes ----
__global__ __launch_bounds__(256) void bin_edges(
    const int* __restrict__ src, const int* __restrict__ dst,
    int* __restrict__ cursor, int* __restrict__ binned, int E, int NB)
{
    __shared__ int lh[512];
    __shared__ int lcur[512];
    int tid = threadIdx.x;
    for (int j = tid; j < NB; j += 256) lh[j] = 0;
    __syncthreads();
    int e0 = blockIdx.x * CHUNK;
    int ee = min(e0 + CHUNK, E);
    for (int i = e0 + tid; i < ee; i += 256) atomicAdd(&lh[dst[i] >> BSH], 1);
    __syncthreads();
    for (int j = tid; j < NB; j += 256) {
        int c = lh[j];
        if (c) lcur[j] = atomicAdd(&cursor[j], c);  // reserve contiguous range
    }
    __syncthreads();
    for (int i = e0 + tid; i < ee; i += 256) {
        int d = dst[i];
        int p = atomicAdd(&lcur[d >> BSH], 1);      // LDS atomic -> global slot
        binned[p] = (src[i] << BSH) | (d & 255);
    }
}

// ---- per-bucket CSR: rowptr/rowcnt + within-bucket dst-sort of src; dis ----
__global__ __launch_bounds__(1024) void bucket_csr(
    const int* __restrict__ cursor, const int* __restrict__ binned,
    int* __restrict__ rowptr, int* __restrict__ rowcnt, int* __restrict__ sorted_src,
    float* __restrict__ dis, int N)
{
    __shared__ int cnt[256];
    __shared__ int s[256];
    __shared__ int lcur[256];
    int b = blockIdx.x, tid = threadIdx.x;
    int bn = b << BSH;
    if (tid < 256) cnt[tid] = 0;
    __syncthreads();
    int es = b * CAP, ee = cursor[b];
    for (int i = es + tid; i < ee; i += 1024) atomicAdd(&cnt[binned[i] & 255], 1);
    __syncthreads();
    int v = 0;
    if (tid < 256) { v = cnt[tid]; s[tid] = v; }
    __syncthreads();
    for (int off = 1; off < 256; off <<= 1) {
        int t = 0;
        if (tid < 256 && tid >= off) t = s[tid - off];
        __syncthreads();
        if (tid < 256) s[tid] += t;
        __syncthreads();
    }
    if (tid < 256) {
        int ex = s[tid] - v;   // exclusive scan
        lcur[tid] = ex;
        int n = bn + tid;
        if (n < N) {
            rowptr[n] = es + ex;
            rowcnt[n] = v;
            dis[n] = rsqrtf((float)(v + 1));
        }
    }
    __syncthreads();
    for (int i = es + tid; i < ee; i += 1024) {
        int e = binned[i];
        int p = atomicAdd(&lcur[e & 255], 1);
        sorted_src[es + p] = e >> BSH;
    }
}

// ---- embed + ALL node-local products:
//   h0 = x@We + be                    (registers/LDS only, never stored)
//   g1 = bf16(dis * (h0@W1))
//   y2 = bf16(h0 @ W2[32:64])         (second half of layer-2 GEMM)
//   hp = h0 @ Wp[32:] + bp + x[:,1]   (second half of prediction head)
__global__ __launch_bounds__(256) void embed_g1(
    const float* __restrict__ x, const float* __restrict__ We,
    const float* __restrict__ be, const float* __restrict__ W1,
    const float* __restrict__ W2, const float* __restrict__ Wp,
    const float* __restrict__ bp, const float* __restrict__ dis,
    __hip_bfloat16* __restrict__ g, __hip_bfloat16* __restrict__ y2,
    float* __restrict__ hp, int N)
{
    __shared__ float sWe[NF * H];
    __shared__ float sW1[H * H];
    __shared__ float sW2b[H * H];   // W2 rows 32..63
    __shared__ float sbe[H];
    __shared__ float sWpb[H];       // Wp[32..63]
    __shared__ float sx[8][NF];
    __shared__ float sh[8][H];

    int tid = threadIdx.x;
    for (int j = tid; j < NF * H; j += 256) sWe[j] = We[j];
    for (int j = tid; j < H * H; j += 256) sW1[j] = W1[j];
    for (int j = tid; j < H * H; j += 256) sW2b[j] = W2[H * H + j];
    if (tid < H) sbe[tid] = be[tid];
    if (tid >= H && tid < 2 * H) sWpb[tid - H] = Wp[tid];

    int grp = tid >> 5, t = tid & 31;
    int node = blockIdx.x * 8 + grp;
    int nodec = node < N ? node : N - 1;
    if (t < NF) sx[grp][t] = x[(size_t)nodec * NF + t];
    __syncthreads();

    float h = sbe[t];
#pragma unroll
    for (int k = 0; k < NF; k++) h += sx[grp][k] * sWe[k * H + t];
    sh[grp][t] = h;
    __syncthreads();

    float di = dis[nodec];
    float gv = 0.f, yv = 0.f;
#pragma unroll
    for (int k = 0; k < H; k++) {
        float hv = sh[grp][k];
        gv += hv * sW1[k * H + t];
        yv += hv * sW2b[k * H + t];
    }
    gv *= di;

    float pv = h * sWpb[t];
#pragma unroll
    for (int off = 16; off > 0; off >>= 1) pv += __shfl_down(pv, off, 32);

    if (node < N) {
        size_t o = (size_t)node * H + t;
        g[o] = __float2bfloat16(gv);
        y2[o] = __float2bfloat16(yv);
        if (t == 0) hp[node] = pv + bp[0] + sx[grp][1];
    }
}

// ---- fused gather #1 + mid layer, 16 lanes/node, bf16x2 loads:
//   a = g1[d]+sum g1[src]; r1 = relu(dis*a+b1); g2 = bf16(dis*(r1@W2[:32] + y2))
__global__ __launch_bounds__(256) void agg_mid(
    const int* __restrict__ rowptr, const int* __restrict__ rowcnt,
    const int* __restrict__ sorted_src,
    const __hip_bfloat16* __restrict__ g_in, const __hip_bfloat16* __restrict__ y2,
    const float* __restrict__ dis, const float* __restrict__ W2,
    const float* __restrict__ b1, __hip_bfloat16* __restrict__ g_out, int N)
{
    __shared__ float sW2[H * H];     // W2 rows 0..31 only
    __shared__ float srow[16][33];   // pad 33: k-reads hit distinct banks per group

    int tid = threadIdx.x;
    for (int j = tid; j < H * H; j += 256) sW2[j] = W2[j];

    int grp = tid >> 4, lane = tid & 15;
    int node = blockIdx.x * 16 + grp;
    int nodec = node < N ? node : N - 1;

    const unsigned int* gv = (const unsigned int*)g_in;
    unsigned int sv = gv[(size_t)nodec * 16 + lane];
    float ax = bflo(sv), ay = bfhi(sv);   // self-loop term, 2 cols/lane

    int start = rowptr[nodec];
    int end = start + rowcnt[nodec];
    int i = start;
    for (; i + 7 < end; i += 8) {
        int s0 = sorted_src[i],     s1 = sorted_src[i + 1];
        int s2 = sorted_src[i + 2], s3 = sorted_src[i + 3];
        int s4 = sorted_src[i + 4], s5 = sorted_src[i + 5];
        int s6 = sorted_src[i + 6], s7 = sorted_src[i + 7];
        unsigned int v0 = gv[(size_t)s0 * 16 + lane], v1 = gv[(size_t)s1 * 16 + lane];
        unsigned int v2 = gv[(size_t)s2 * 16 + lane], v3 = gv[(size_t)s3 * 16 + lane];
        unsigned int v4 = gv[(size_t)s4 * 16 + lane], v5 = gv[(size_t)s5 * 16 + lane];
        unsigned int v6 = gv[(size_t)s6 * 16 + lane], v7 = gv[(size_t)s7 * 16 + lane];
        ax += bflo(v0) + bflo(v1) + bflo(v2) + bflo(v3)
            + bflo(v4) + bflo(v5) + bflo(v6) + bflo(v7);
        ay += bfhi(v0) + bfhi(v1) + bfhi(v2) + bfhi(v3)
            + bfhi(v4) + bfhi(v5) + bfhi(v6) + bfhi(v7);
    }
    for (; i + 3 < end; i += 4) {
        int s0 = sorted_src[i],     s1 = sorted_src[i + 1];
        int s2 = sorted_src[i + 2], s3 = sorted_src[i + 3];
        unsigned int v0 = gv[(size_t)s0 * 16 + lane], v1 = gv[(size_t)s1 * 16 + lane];
        unsigned int v2 = gv[(size_t)s2 * 16 + lane], v3 = gv[(size_t)s3 * 16 + lane];
        ax += bflo(v0) + bflo(v1) + bflo(v2) + bflo(v3);
        ay += bfhi(v0) + bfhi(v1) + bfhi(v2) + bfhi(v3);
    }
    for (; i < end; i++) {
        unsigned int v = gv[(size_t)sorted_src[i] * 16 + lane];
        ax += bflo(v); ay += bfhi(v);
    }

    float di = dis[nodec];
    float2 bb = ((const float2*)b1)[lane];
    srow[grp][2 * lane]     = fmaxf(di * ax + bb.x, 0.f);
    srow[grp][2 * lane + 1] = fmaxf(di * ay + bb.y, 0.f);
    __syncthreads();   // covers sW2 staging AND srow writes

    const float2* sW2v = (const float2*)sW2;
    float o0 = 0.f, o1 = 0.f;
#pragma unroll
    for (int k = 0; k < H; k++) {
        float rv = srow[grp][k];
        float2 w = sW2v[k * 16 + lane];
        o0 += rv * w.x;
        o1 += rv * w.y;
    }
    unsigned int yv = ((const unsigned int*)y2)[(size_t)nodec * 16 + lane];
    o0 = di * (o0 + bflo(yv));
    o1 = di * (o1 + bfhi(yv));

    if (node < N) {
        __hip_bfloat162 p;
        p.x = __float2bfloat16(o0);
        p.y = __float2bfloat16(o1);
        ((__hip_bfloat162*)g_out)[(size_t)node * 16 + lane] = p;
    }
}

// ---- fused gather #2 + prediction head, 16 lanes/node:
//   out = relu( sum_c relu(dis*a+b2)[c]*Wp[c] + hp[n] )
__global__ __launch_bounds__(256) void agg_final(
    const int* __restrict__ rowptr, const int* __restrict__ rowcnt,
    const int* __restrict__ sorted_src,
    const __hip_bfloat16* __restrict__ g_in, const float* __restrict__ hp,
    const float* __restrict__ dis, const float* __restrict__ b2,
    const float* __restrict__ Wp, float* __restrict__ out, int N)
{
    int gid = blockIdx.x * blockDim.x + threadIdx.x;
    int node = gid >> 4;
    if (node >= N) return;
    int lane = gid & 15;

    const unsigned int* gv = (const unsigned int*)g_in;
    unsigned int sv = gv[(size_t)node * 16 + lane];
    float ax = bflo(sv), ay = bfhi(sv);

    int start = rowptr[node];
    int end = start + rowcnt[node];
    int i = start;
    for (; i + 7 < end; i += 8) {
        int s0 = sorted_src[i],     s1 = sorted_src[i + 1];
        int s2 = sorted_src[i + 2], s3 = sorted_src[i + 3];
        int s4 = sorted_src[i + 4], s5 = sorted_src[i + 5];
        int s6 = sorted_src[i + 6], s7 = sorted_src[i + 7];
        unsigned int v0 = gv[(size_t)s0 * 16 + lane], v1 = gv[(size_t)s1 * 16 + lane];
        unsigned int v2 = gv[(size_t)s2 * 16 + lane], v3 = gv[(size_t)s3 * 16 + lane];
        unsigned int v4 = gv[(size_t)s4 * 16 + lane], v5 = gv[(size_t)s5 * 16 + lane];
        unsigned int v6 = gv[(size_t)s6 * 16 + lane], v7 = gv[(size_t)s7 * 16 + lane];
        ax += bflo(v0) + bflo(v1) + bflo(v2) + bflo(v3)
            + bflo(v4) + bflo(v5) + bflo(v6) + bflo(v7);
        ay += bfhi(v0) + bfhi(v1) + bfhi(v2) + bfhi(v3)
            + bfhi(v4) + bfhi(v5) + bfhi(v6) + bfhi(v7);
    }
    for (; i + 3 < end; i += 4) {
        int s0 = sorted_src[i],     s1 = sorted_src[i + 1];
        int s2 = sorted_src[i + 2], s3 = sorted_src[i + 3];
        unsigned int v0 = gv[(size_t)s0 * 16 + lane], v1 = gv[(size_t)s1 * 16 + lane];
        unsigned int v2 = gv[(size_t)s2 * 16 + lane], v3 = gv[(size_t)s3 * 16 + lane];
        ax += bflo(v0) + bflo(v1) + bflo(v2) + bflo(v3);
        ay += bfhi(v0) + bfhi(v1) + bfhi(v2) + bfhi(v3);
    }
    for (; i < end; i++) {
        unsigned int v = gv[(size_t)sorted_src[i] * 16 + lane];
        ax += bflo(v); ay += bfhi(v);
    }

    float di = dis[node];
    float2 b2v = ((const float2*)b2)[lane];
    float2 wpa = ((const float2*)Wp)[lane];
    float v = fmaxf(di * ax + b2v.x, 0.f) * wpa.x
            + fmaxf(di * ay + b2v.y, 0.f) * wpa.y;
#pragma unroll
    for (int off = 8; off > 0; off >>= 1) v += __shfl_down(v, off, 16);
    if (lane == 0) out[node] = fmaxf(v + hp[node], 0.f);
}

extern "C" void kernel_launch(void* const* d_in, const int* in_sizes, int n_in,
                              void* d_out, int out_size, void* d_ws, size_t ws_size,
                              hipStream_t stream) {
    const float* x  = (const float*)d_in[0];
    const int*   ei = (const int*)d_in[1];
    const float* We = (const float*)d_in[2];
    const float* be = (const float*)d_in[3];
    const float* W1 = (const float*)d_in[4];
    const float* b1 = (const float*)d_in[5];
    const float* W2 = (const float*)d_in[6];
    const float* b2 = (const float*)d_in[7];
    const float* Wp = (const float*)d_in[8];
    const float* bp = (const float*)d_in[9];
    float* out = (float*)d_out;

    const int N = in_sizes[0] / NF;
    const int E = in_sizes[1] / 2;
    const int* src = ei;
    const int* dst = ei + E;
    const int NB = (N + 255) >> BSH;              // 391
    const int nchunk = (E + CHUNK - 1) / CHUNK;   // 782

    // workspace layout
    size_t Np  = ((size_t)N + 127) & ~(size_t)127;
    size_t NHp = ((size_t)N * H + 127) & ~(size_t)127;
    float* ws  = (float*)d_ws;
    float* dis = ws;                      // Np
    float* hp  = dis + Np;                // Np
    __hip_bfloat16* g1 = (__hip_bfloat16*)(hp + Np);   // NHp bf16
    __hip_bfloat16* g2 = g1 + NHp;                     // NHp bf16
    __hip_bfloat16* y2 = g2 + NHp;                     // NHp bf16
    int* cursor     = (int*)(y2 + NHp);   // 512
    int* rowptr     = cursor + 512;       // Np
    int* rowcnt     = rowptr + Np;        // Np
    int* binned     = rowcnt + Np;        // NB*CAP
    int* sorted_src = binned + (size_t)NB * CAP;  // NB*CAP

    init_cur<<<2, 256, 0, stream>>>(cursor, NB);
    bin_edges<<<nchunk, 256, 0, stream>>>(src, dst, cursor, binned, E, NB);
    bucket_csr<<<NB, 1024, 0, stream>>>(cursor, binned, rowptr, rowcnt, sorted_src, dis, N);

    embed_g1<<<(N + 7) / 8, 256, 0, stream>>>(x, We, be, W1, W2, Wp, bp, dis, g1, y2, hp, N);
    agg_mid<<<(N + 15) / 16, 256, 0, stream>>>(rowptr, rowcnt, sorted_src, g1, y2, dis, W2, b1, g2, N);
    agg_final<<<((size_t)N * 16 + 255) / 256, 256, 0, stream>>>(rowptr, rowcnt, sorted_src, g2, hp, dis, b2, Wp, out, N);
}

// Round 11
// 217.585 us; speedup vs baseline: 1.0274x; 1.0274x over previous
//
#include <hip/hip_runtime.h>
#include <hip/hip_bf16.h>

#define NF 22     // node features
#define H  32     // hidden dim
#define BSH 8     // 256 nodes per bucket
#define CAP 8192  // edge capacity per bucket (mean 4092 at E=1.6M, NB=391)
#define CHUNK 2048
// requires N <= 131072 (src fits 24 bits after <<8 shift; bucket count <= 512)

__device__ __forceinline__ float bflo(unsigned int v) { return __uint_as_float(v << 16); }
__device__ __forceinline__ float bfhi(unsigned int v) { return __uint_as_float(v & 0xffff0000u); }
__device__ __forceinline__ unsigned int packbf2(float a, float b) {
    __hip_bfloat162 p; p.x = __float2bfloat16(a); p.y = __float2bfloat16(b);
    return *(unsigned int*)&p;
}

// ---- init per-bucket cursors to fixed-capacity bases ----
__global__ void init_cur(int* __restrict__ cursor, int NB) {
    int i = blockIdx.x * blockDim.x + threadIdx.x;
    if (i < NB) cursor[i] = i * CAP;
}

// ---- bin edges by dst bucket; packed (src<<8)|(dst&255); dense reserved writes ----
__global__ __launch_bounds__(256) void bin_edges(
    const int* __restrict__ src, const int* __restrict__ dst,
    int* __restrict__ cursor, int* __restrict__ binned, int E, int NB)
{
    __shared__ int lh[512];
    __shared__ int lcur[512];
    int tid = threadIdx.x;
    for (int j = tid; j < NB; j += 256) lh[j] = 0;
    __syncthreads();
    int e0 = blockIdx.x * CHUNK;
    int ee = min(e0 + CHUNK, E);
    for (int i = e0 + tid; i < ee; i += 256) atomicAdd(&lh[dst[i] >> BSH], 1);
    __syncthreads();
    for (int j = tid; j < NB; j += 256) {
        int c = lh[j];
        if (c) lcur[j] = atomicAdd(&cursor[j], c);  // reserve contiguous range
    }
    __syncthreads();
    for (int i = e0 + tid; i < ee; i += 256) {
        int d = dst[i];
        int p = atomicAdd(&lcur[d >> BSH], 1);      // LDS atomic -> global slot
        binned[p] = (src[i] << BSH) | (d & 255);
    }
}

// ---- per-bucket CSR: rowptr/rowcnt + within-bucket dst-sort of src; dis ----
__global__ __launch_bounds__(1024) void bucket_csr(
    const int* __restrict__ cursor, const int* __restrict__ binned,
    int* __restrict__ rowptr, int* __restrict__ rowcnt, int* __restrict__ sorted_src,
    float* __restrict__ dis, int N)
{
    __shared__ int cnt[256];
    __shared__ int s[256];
    __shared__ int lcur[256];
    int b = blockIdx.x, tid = threadIdx.x;
    int bn = b << BSH;
    if (tid < 256) cnt[tid] = 0;
    __syncthreads();
    int es = b * CAP, ee = cursor[b];
    for (int i = es + tid; i < ee; i += 1024) atomicAdd(&cnt[binned[i] & 255], 1);
    __syncthreads();
    int v = 0;
    if (tid < 256) { v = cnt[tid]; s[tid] = v; }
    __syncthreads();
    for (int off = 1; off < 256; off <<= 1) {
        int t = 0;
        if (tid < 256 && tid >= off) t = s[tid - off];
        __syncthreads();
        if (tid < 256) s[tid] += t;
        __syncthreads();
    }
    if (tid < 256) {
        int ex = s[tid] - v;   // exclusive scan
        lcur[tid] = ex;
        int n = bn + tid;
        if (n < N) {
            rowptr[n] = es + ex;
            rowcnt[n] = v;
            dis[n] = rsqrtf((float)(v + 1));
        }
    }
    __syncthreads();
    for (int i = es + tid; i < ee; i += 1024) {
        int e = binned[i];
        int p = atomicAdd(&lcur[e & 255], 1);
        sorted_src[es + p] = e >> BSH;
    }
}

// ---- embed + ALL node-local products (grid-stride: stage weights ONCE/block):
//   h0 = x@We + be   (registers/LDS only)
//   g1 = bf16(dis * (h0@W1)) ; y2 = bf16(h0 @ W2[32:64]) ; hp = h0@Wp[32:]+bp+x[:,1]
__global__ __launch_bounds__(256) void embed_g1(
    const float* __restrict__ x, const float* __restrict__ We,
    const float* __restrict__ be, const float* __restrict__ W1,
    const float* __restrict__ W2, const float* __restrict__ Wp,
    const float* __restrict__ bp, const float* __restrict__ dis,
    __hip_bfloat16* __restrict__ g, __hip_bfloat16* __restrict__ y2,
    float* __restrict__ hp, int N)
{
    __shared__ float sWe[NF * H];
    __shared__ float sW1[H * H];
    __shared__ float sW2b[H * H];   // W2 rows 32..63
    __shared__ float sbe[H];
    __shared__ float sWpb[H];       // Wp[32..63]
    __shared__ float sx[8][NF];
    __shared__ float sh[8][H];

    int tid = threadIdx.x;
    for (int j = tid; j < NF * H; j += 256) sWe[j] = We[j];
    for (int j = tid; j < H * H; j += 256) sW1[j] = W1[j];
    for (int j = tid; j < H * H; j += 256) sW2b[j] = W2[H * H + j];
    if (tid < H) sbe[tid] = be[tid];
    if (tid >= H && tid < 2 * H) sWpb[tid - H] = Wp[tid];

    int grp = tid >> 5, t = tid & 31;
    int ngrp = (N + 7) >> 3;
    for (int nb = blockIdx.x; nb < ngrp; nb += gridDim.x) {
        int node = nb * 8 + grp;
        int nodec = node < N ? node : N - 1;
        __syncthreads();   // prior-iteration sh/sx reads done; also covers weight staging
        if (t < NF) sx[grp][t] = x[(size_t)nodec * NF + t];
        __syncthreads();

        float h = sbe[t];
#pragma unroll
        for (int k = 0; k < NF; k++) h += sx[grp][k] * sWe[k * H + t];
        sh[grp][t] = h;
        __syncthreads();

        float di = dis[nodec];
        float gv = 0.f, yv = 0.f;
#pragma unroll
        for (int k = 0; k < H; k++) {
            float hv = sh[grp][k];
            gv += hv * sW1[k * H + t];
            yv += hv * sW2b[k * H + t];
        }
        gv *= di;

        float pv = h * sWpb[t];
#pragma unroll
        for (int off = 16; off > 0; off >>= 1) pv += __shfl_down(pv, off, 32);

        if (node < N) {
            size_t o = (size_t)node * H + t;
            g[o] = __float2bfloat16(gv);
            y2[o] = __float2bfloat16(yv);
            if (t == 0) hp[node] = pv + bp[0] + sx[grp][1];
        }
    }
}

// ---- fused gather #1 + mid layer, 8 lanes/node, uint2 (4 bf16) loads:
//   a = g1[d]+sum g1[src]; r1 = relu(dis*a+b1); g2 = bf16(dis*(r1@W2[:32] + y2))
__global__ __launch_bounds__(256) void agg_mid(
    const int* __restrict__ rowptr, const int* __restrict__ rowcnt,
    const int* __restrict__ sorted_src,
    const __hip_bfloat16* __restrict__ g_in, const __hip_bfloat16* __restrict__ y2,
    const float* __restrict__ dis, const float* __restrict__ W2,
    const float* __restrict__ b1, __hip_bfloat16* __restrict__ g_out, int N)
{
    __shared__ float sW2[H * H];     // W2 rows 0..31
    __shared__ float srow[32][33];

    int tid = threadIdx.x;
    for (int j = tid; j < H * H; j += 256) sW2[j] = W2[j];

    int grp = tid >> 3, lane = tid & 7;   // 32 nodes/block, 8 lanes/node
    int node = blockIdx.x * 32 + grp;
    int nodec = node < N ? node : N - 1;

    const uint2* gv2 = (const uint2*)g_in;   // row = 8 uint2
    uint2 sv = gv2[(size_t)nodec * 8 + lane];
    float a0 = bflo(sv.x), a1 = bfhi(sv.x), a2 = bflo(sv.y), a3 = bfhi(sv.y);

    int start = rowptr[nodec];
    int end = start + rowcnt[nodec];
    int i = start;
    for (; i + 7 < end; i += 8) {
        int s0 = sorted_src[i],     s1 = sorted_src[i + 1];
        int s2 = sorted_src[i + 2], s3 = sorted_src[i + 3];
        int s4 = sorted_src[i + 4], s5 = sorted_src[i + 5];
        int s6 = sorted_src[i + 6], s7 = sorted_src[i + 7];
        uint2 v0 = gv2[(size_t)s0 * 8 + lane], v1 = gv2[(size_t)s1 * 8 + lane];
        uint2 v2 = gv2[(size_t)s2 * 8 + lane], v3 = gv2[(size_t)s3 * 8 + lane];
        uint2 v4 = gv2[(size_t)s4 * 8 + lane], v5 = gv2[(size_t)s5 * 8 + lane];
        uint2 v6 = gv2[(size_t)s6 * 8 + lane], v7 = gv2[(size_t)s7 * 8 + lane];
        a0 += bflo(v0.x) + bflo(v1.x) + bflo(v2.x) + bflo(v3.x)
            + bflo(v4.x) + bflo(v5.x) + bflo(v6.x) + bflo(v7.x);
        a1 += bfhi(v0.x) + bfhi(v1.x) + bfhi(v2.x) + bfhi(v3.x)
            + bfhi(v4.x) + bfhi(v5.x) + bfhi(v6.x) + bfhi(v7.x);
        a2 += bflo(v0.y) + bflo(v1.y) + bflo(v2.y) + bflo(v3.y)
            + bflo(v4.y) + bflo(v5.y) + bflo(v6.y) + bflo(v7.y);
        a3 += bfhi(v0.y) + bfhi(v1.y) + bfhi(v2.y) + bfhi(v3.y)
            + bfhi(v4.y) + bfhi(v5.y) + bfhi(v6.y) + bfhi(v7.y);
    }
    for (; i < end; i++) {
        uint2 v = gv2[(size_t)sorted_src[i] * 8 + lane];
        a0 += bflo(v.x); a1 += bfhi(v.x); a2 += bflo(v.y); a3 += bfhi(v.y);
    }

    float di = dis[nodec];
    float4 bb = ((const float4*)b1)[lane];
    srow[grp][4 * lane]     = fmaxf(di * a0 + bb.x, 0.f);
    srow[grp][4 * lane + 1] = fmaxf(di * a1 + bb.y, 0.f);
    srow[grp][4 * lane + 2] = fmaxf(di * a2 + bb.z, 0.f);
    srow[grp][4 * lane + 3] = fmaxf(di * a3 + bb.w, 0.f);
    __syncthreads();   // covers sW2 staging AND srow writes

    const float4* sW2v = (const float4*)sW2;
    float o0 = 0.f, o1 = 0.f, o2 = 0.f, o3 = 0.f;
#pragma unroll
    for (int k = 0; k < H; k++) {
        float rv = srow[grp][k];           // broadcast within group
        float4 w = sW2v[k * 8 + lane];
        o0 += rv * w.x; o1 += rv * w.y; o2 += rv * w.z; o3 += rv * w.w;
    }
    uint2 yv = ((const uint2*)y2)[(size_t)nodec * 8 + lane];
    o0 = di * (o0 + bflo(yv.x));
    o1 = di * (o1 + bfhi(yv.x));
    o2 = di * (o2 + bflo(yv.y));
    o3 = di * (o3 + bfhi(yv.y));

    if (node < N) {
        uint2 p;
        p.x = packbf2(o0, o1);
        p.y = packbf2(o2, o3);
        ((uint2*)g_out)[(size_t)node * 8 + lane] = p;
    }
}

// ---- fused gather #2 + prediction head, 8 lanes/node:
//   out = relu( sum_c relu(dis*a+b2)[c]*Wp[c] + hp[n] )
__global__ __launch_bounds__(256) void agg_final(
    const int* __restrict__ rowptr, const int* __restrict__ rowcnt,
    const int* __restrict__ sorted_src,
    const __hip_bfloat16* __restrict__ g_in, const float* __restrict__ hp,
    const float* __restrict__ dis, const float* __restrict__ b2,
    const float* __restrict__ Wp, float* __restrict__ out, int N)
{
    int gid = blockIdx.x * blockDim.x + threadIdx.x;
    int node = gid >> 3;
    if (node >= N) return;
    int lane = gid & 7;

    const uint2* gv2 = (const uint2*)g_in;
    uint2 sv = gv2[(size_t)node * 8 + lane];
    float a0 = bflo(sv.x), a1 = bfhi(sv.x), a2 = bflo(sv.y), a3 = bfhi(sv.y);

    int start = rowptr[node];
    int end = start + rowcnt[node];
    int i = start;
    for (; i + 7 < end; i += 8) {
        int s0 = sorted_src[i],     s1 = sorted_src[i + 1];
        int s2 = sorted_src[i + 2], s3 = sorted_src[i + 3];
        int s4 = sorted_src[i + 4], s5 = sorted_src[i + 5];
        int s6 = sorted_src[i + 6], s7 = sorted_src[i + 7];
        uint2 v0 = gv2[(size_t)s0 * 8 + lane], v1 = gv2[(size_t)s1 * 8 + lane];
        uint2 v2 = gv2[(size_t)s2 * 8 + lane], v3 = gv2[(size_t)s3 * 8 + lane];
        uint2 v4 = gv2[(size_t)s4 * 8 + lane], v5 = gv2[(size_t)s5 * 8 + lane];
        uint2 v6 = gv2[(size_t)s6 * 8 + lane], v7 = gv2[(size_t)s7 * 8 + lane];
        a0 += bflo(v0.x) + bflo(v1.x) + bflo(v2.x) + bflo(v3.x)
            + bflo(v4.x) + bflo(v5.x) + bflo(v6.x) + bflo(v7.x);
        a1 += bfhi(v0.x) + bfhi(v1.x) + bfhi(v2.x) + bfhi(v3.x)
            + bfhi(v4.x) + bfhi(v5.x) + bfhi(v6.x) + bfhi(v7.x);
        a2 += bflo(v0.y) + bflo(v1.y) + bflo(v2.y) + bflo(v3.y)
            + bflo(v4.y) + bflo(v5.y) + bflo(v6.y) + bflo(v7.y);
        a3 += bfhi(v0.y) + bfhi(v1.y) + bfhi(v2.y) + bfhi(v3.y)
            + bfhi(v4.y) + bfhi(v5.y) + bfhi(v6.y) + bfhi(v7.y);
    }
    for (; i < end; i++) {
        uint2 v = gv2[(size_t)sorted_src[i] * 8 + lane];
        a0 += bflo(v.x); a1 += bfhi(v.x); a2 += bflo(v.y); a3 += bfhi(v.y);
    }

    float di = dis[node];
    float4 b2v = ((const float4*)b2)[lane];
    float4 wp  = ((const float4*)Wp)[lane];
    float v = fmaxf(di * a0 + b2v.x, 0.f) * wp.x
            + fmaxf(di * a1 + b2v.y, 0.f) * wp.y
            + fmaxf(di * a2 + b2v.z, 0.f) * wp.z
            + fmaxf(di * a3 + b2v.w, 0.f) * wp.w;
#pragma unroll
    for (int off = 4; off > 0; off >>= 1) v += __shfl_down(v, off, 8);
    if (lane == 0) out[node] = fmaxf(v + hp[node], 0.f);
}

extern "C" void kernel_launch(void* const* d_in, const int* in_sizes, int n_in,
                              void* d_out, int out_size, void* d_ws, size_t ws_size,
                              hipStream_t stream) {
    const float* x  = (const float*)d_in[0];
    const int*   ei = (const int*)d_in[1];
    const float* We = (const float*)d_in[2];
    const float* be = (const float*)d_in[3];
    const float* W1 = (const float*)d_in[4];
    const float* b1 = (const float*)d_in[5];
    const float* W2 = (const float*)d_in[6];
    const float* b2 = (const float*)d_in[7];
    const float* Wp = (const float*)d_in[8];
    const float* bp = (const float*)d_in[9];
    float* out = (float*)d_out;

    const int N = in_sizes[0] / NF;
    const int E = in_sizes[1] / 2;
    const int* src = ei;
    const int* dst = ei + E;
    const int NB = (N + 255) >> BSH;              // 391
    const int nchunk = (E + CHUNK - 1) / CHUNK;   // 782

    // workspace layout
    size_t Np  = ((size_t)N + 127) & ~(size_t)127;
    size_t NHp = ((size_t)N * H + 127) & ~(size_t)127;
    float* ws  = (float*)d_ws;
    float* dis = ws;                      // Np
    float* hp  = dis + Np;                // Np
    __hip_bfloat16* g1 = (__hip_bfloat16*)(hp + Np);   // NHp bf16
    __hip_bfloat16* g2 = g1 + NHp;                     // NHp bf16
    __hip_bfloat16* y2 = g2 + NHp;                     // NHp bf16
    int* cursor     = (int*)(y2 + NHp);   // 512
    int* rowptr     = cursor + 512;       // Np
    int* rowcnt     = rowptr + Np;        // Np
    int* binned     = rowcnt + Np;        // NB*CAP
    int* sorted_src = binned + (size_t)NB * CAP;  // NB*CAP

    init_cur<<<2, 256, 0, stream>>>(cursor, NB);
    bin_edges<<<nchunk, 256, 0, stream>>>(src, dst, cursor, binned, E, NB);
    bucket_csr<<<NB, 1024, 0, stream>>>(cursor, binned, rowptr, rowcnt, sorted_src, dis, N);

    int ngrp = (N + 7) >> 3;
    int eg = ngrp < 1536 ? ngrp : 1536;
    embed_g1<<<eg, 256, 0, stream>>>(x, We, be, W1, W2, Wp, bp, dis, g1, y2, hp, N);
    agg_mid<<<(N + 31) / 32, 256, 0, stream>>>(rowptr, rowcnt, sorted_src, g1, y2, dis, W2, b1, g2, N);
    agg_final<<<((size_t)N * 8 + 255) / 256, 256, 0, stream>>>(rowptr, rowcnt, sorted_src, g2, hp, dis, b2, Wp, out, N);
}

// Round 12
// 196.331 us; speedup vs baseline: 1.1386x; 1.1083x over previous
//
#include <hip/hip_runtime.h>
#include <hip/hip_bf16.h>

#define NF 22     // node features
#define H  32     // hidden dim
#define BSH 8     // 256 nodes per bucket
#define CAP 8192  // edge capacity per bucket (mean 4092 at E=1.6M, NB=391)
#define BCHUNK 4096
// requires N <= 131072 (src fits 24 bits after <<8 shift; bucket count <= 512)

__device__ __forceinline__ float bflo(unsigned int v) { return __uint_as_float(v << 16); }
__device__ __forceinline__ float bfhi(unsigned int v) { return __uint_as_float(v & 0xffff0000u); }
__device__ __forceinline__ unsigned int packbf2(float a, float b) {
    __hip_bfloat162 p; p.x = __float2bfloat16(a); p.y = __float2bfloat16(b);
    return *(unsigned int*)&p;
}

// ---- init per-bucket cursors to fixed-capacity bases ----
__global__ void init_cur(int* __restrict__ cursor, int NB) {
    int i = blockIdx.x * blockDim.x + threadIdx.x;
    if (i < NB) cursor[i] = i * CAP;
}

// ---- bin edges by dst bucket via per-chunk LDS counting sort; coalesced writes ----
__global__ __launch_bounds__(512) void bin_edges(
    const int* __restrict__ src, const int* __restrict__ dst,
    int* __restrict__ cursor, int* __restrict__ binned, int E, int NB)
{
    __shared__ int vals[BCHUNK];              // packed (src<<8)|(dst&255)
    __shared__ unsigned short bkts[BCHUNK];   // bucket id per staged edge
    __shared__ int svals[BCHUNK];             // bucket-sorted packed edges
    __shared__ unsigned short sbkt[BCHUNK];   // bucket id per sorted slot
    __shared__ int scnt[512];                 // per-bucket count (frozen)
    __shared__ int sex[512];                  // per-bucket exclusive start (frozen)
    __shared__ int lcur[512];                 // scatter cursor
    __shared__ int gbase[512];                // reserved global base

    int tid = threadIdx.x;
    for (int j = tid; j < NB; j += 512) scnt[j] = 0;
    __syncthreads();

    int e0 = blockIdx.x * BCHUNK;
    int n = min(e0 + BCHUNK, E) - e0;

    // phase A: stage + histogram
    for (int i = tid; i < n; i += 512) {
        int d = dst[e0 + i];
        int b = d >> BSH;
        vals[i] = (src[e0 + i] << BSH) | (d & 255);
        bkts[i] = (unsigned short)b;
        atomicAdd(&scnt[b], 1);
    }
    __syncthreads();

    // phase B: LDS scan (Hillis-Steele over 512) -> exclusive starts
    int c = (tid < NB) ? scnt[tid] : 0;
    int acc = c;
    sex[tid] = acc;   // temporarily inclusive
    __syncthreads();
    for (int off = 1; off < 512; off <<= 1) {
        int t = (tid >= off) ? sex[tid - off] : 0;
        __syncthreads();
        sex[tid] += t;
        __syncthreads();
    }
    int ex = sex[tid] - acc;   // exclusive
    __syncthreads();
    sex[tid] = ex;
    lcur[tid] = ex;
    // reserve global range (one atomic per non-empty bucket)
    if (tid < NB && c) gbase[tid] = atomicAdd(&cursor[tid], c);
    __syncthreads();

    // phase C: scatter into sorted LDS order
    for (int i = tid; i < n; i += 512) {
        int b = bkts[i];
        int p = atomicAdd(&lcur[b], 1);
        svals[p] = vals[i];
        sbkt[p] = (unsigned short)b;
    }
    __syncthreads();

    // phase D: coalesced copy-out (consecutive lanes -> consecutive positions)
    for (int i = tid; i < n; i += 512) {
        int b = sbkt[i];
        binned[gbase[b] + (i - sex[b])] = svals[i];
    }
}

// ---- per-bucket CSR: rowptr/rowcnt + within-bucket dst-sort of src; dis ----
__global__ __launch_bounds__(1024) void bucket_csr(
    const int* __restrict__ cursor, const int* __restrict__ binned,
    int* __restrict__ rowptr, int* __restrict__ rowcnt, int* __restrict__ sorted_src,
    float* __restrict__ dis, int N)
{
    __shared__ int cnt[256];
    __shared__ int s[256];
    __shared__ int lcur[256];
    int b = blockIdx.x, tid = threadIdx.x;
    int bn = b << BSH;
    if (tid < 256) cnt[tid] = 0;
    __syncthreads();
    int es = b * CAP, ee = cursor[b];
    for (int i = es + tid; i < ee; i += 1024) atomicAdd(&cnt[binned[i] & 255], 1);
    __syncthreads();
    int v = 0;
    if (tid < 256) { v = cnt[tid]; s[tid] = v; }
    __syncthreads();
    for (int off = 1; off < 256; off <<= 1) {
        int t = 0;
        if (tid < 256 && tid >= off) t = s[tid - off];
        __syncthreads();
        if (tid < 256) s[tid] += t;
        __syncthreads();
    }
    if (tid < 256) {
        int ex = s[tid] - v;   // exclusive scan
        lcur[tid] = ex;
        int n = bn + tid;
        if (n < N) {
            rowptr[n] = es + ex;
            rowcnt[n] = v;
            dis[n] = rsqrtf((float)(v + 1));
        }
    }
    __syncthreads();
    for (int i = es + tid; i < ee; i += 1024) {
        int e = binned[i];
        int p = atomicAdd(&lcur[e & 255], 1);
        sorted_src[es + p] = e >> BSH;
    }
}

// ---- embed + ALL node-local products (grid-stride: stage weights ONCE/block) ----
__global__ __launch_bounds__(256) void embed_g1(
    const float* __restrict__ x, const float* __restrict__ We,
    const float* __restrict__ be, const float* __restrict__ W1,
    const float* __restrict__ W2, const float* __restrict__ Wp,
    const float* __restrict__ bp, const float* __restrict__ dis,
    __hip_bfloat16* __restrict__ g, __hip_bfloat16* __restrict__ y2,
    float* __restrict__ hp, int N)
{
    __shared__ float sWe[NF * H];
    __shared__ float sW1[H * H];
    __shared__ float sW2b[H * H];   // W2 rows 32..63
    __shared__ float sbe[H];
    __shared__ float sWpb[H];       // Wp[32..63]
    __shared__ float sx[8][NF];
    __shared__ float sh[8][H];

    int tid = threadIdx.x;
    for (int j = tid; j < NF * H; j += 256) sWe[j] = We[j];
    for (int j = tid; j < H * H; j += 256) sW1[j] = W1[j];
    for (int j = tid; j < H * H; j += 256) sW2b[j] = W2[H * H + j];
    if (tid < H) sbe[tid] = be[tid];
    if (tid >= H && tid < 2 * H) sWpb[tid - H] = Wp[tid];

    int grp = tid >> 5, t = tid & 31;
    int ngrp = (N + 7) >> 3;
    for (int nb = blockIdx.x; nb < ngrp; nb += gridDim.x) {
        int node = nb * 8 + grp;
        int nodec = node < N ? node : N - 1;
        __syncthreads();   // prior-iteration sh/sx reads done; covers weight staging
        if (t < NF) sx[grp][t] = x[(size_t)nodec * NF + t];
        __syncthreads();

        float h = sbe[t];
#pragma unroll
        for (int k = 0; k < NF; k++) h += sx[grp][k] * sWe[k * H + t];
        sh[grp][t] = h;
        __syncthreads();

        float di = dis[nodec];
        float gv = 0.f, yv = 0.f;
#pragma unroll
        for (int k = 0; k < H; k++) {
            float hv = sh[grp][k];
            gv += hv * sW1[k * H + t];
            yv += hv * sW2b[k * H + t];
        }
        gv *= di;

        float pv = h * sWpb[t];
#pragma unroll
        for (int off = 16; off > 0; off >>= 1) pv += __shfl_down(pv, off, 32);

        if (node < N) {
            size_t o = (size_t)node * H + t;
            g[o] = __float2bfloat16(gv);
            y2[o] = __float2bfloat16(yv);
            if (t == 0) hp[node] = pv + bp[0] + sx[grp][1];
        }
    }
}

// ---- fused gather #1 + mid layer, 8 lanes/node, uint2 (4 bf16) loads ----
__global__ __launch_bounds__(256) void agg_mid(
    const int* __restrict__ rowptr, const int* __restrict__ rowcnt,
    const int* __restrict__ sorted_src,
    const __hip_bfloat16* __restrict__ g_in, const __hip_bfloat16* __restrict__ y2,
    const float* __restrict__ dis, const float* __restrict__ W2,
    const float* __restrict__ b1, __hip_bfloat16* __restrict__ g_out, int N)
{
    __shared__ float sW2[H * H];     // W2 rows 0..31
    __shared__ float srow[32][33];

    int tid = threadIdx.x;
    for (int j = tid; j < H * H; j += 256) sW2[j] = W2[j];

    int grp = tid >> 3, lane = tid & 7;   // 32 nodes/block, 8 lanes/node
    int node = blockIdx.x * 32 + grp;
    int nodec = node < N ? node : N - 1;

    const uint2* gv2 = (const uint2*)g_in;   // row = 8 uint2
    uint2 sv = gv2[(size_t)nodec * 8 + lane];
    float a0 = bflo(sv.x), a1 = bfhi(sv.x), a2 = bflo(sv.y), a3 = bfhi(sv.y);

    int start = rowptr[nodec];
    int end = start + rowcnt[nodec];
    int i = start;
    for (; i + 7 < end; i += 8) {
        int s0 = sorted_src[i],     s1 = sorted_src[i + 1];
        int s2 = sorted_src[i + 2], s3 = sorted_src[i + 3];
        int s4 = sorted_src[i + 4], s5 = sorted_src[i + 5];
        int s6 = sorted_src[i + 6], s7 = sorted_src[i + 7];
        uint2 v0 = gv2[(size_t)s0 * 8 + lane], v1 = gv2[(size_t)s1 * 8 + lane];
        uint2 v2 = gv2[(size_t)s2 * 8 + lane], v3 = gv2[(size_t)s3 * 8 + lane];
        uint2 v4 = gv2[(size_t)s4 * 8 + lane], v5 = gv2[(size_t)s5 * 8 + lane];
        uint2 v6 = gv2[(size_t)s6 * 8 + lane], v7 = gv2[(size_t)s7 * 8 + lane];
        a0 += bflo(v0.x) + bflo(v1.x) + bflo(v2.x) + bflo(v3.x)
            + bflo(v4.x) + bflo(v5.x) + bflo(v6.x) + bflo(v7.x);
        a1 += bfhi(v0.x) + bfhi(v1.x) + bfhi(v2.x) + bfhi(v3.x)
            + bfhi(v4.x) + bfhi(v5.x) + bfhi(v6.x) + bfhi(v7.x);
        a2 += bflo(v0.y) + bflo(v1.y) + bflo(v2.y) + bflo(v3.y)
            + bflo(v4.y) + bflo(v5.y) + bflo(v6.y) + bflo(v7.y);
        a3 += bfhi(v0.y) + bfhi(v1.y) + bfhi(v2.y) + bfhi(v3.y)
            + bfhi(v4.y) + bfhi(v5.y) + bfhi(v6.y) + bfhi(v7.y);
    }
    for (; i < end; i++) {
        uint2 v = gv2[(size_t)sorted_src[i] * 8 + lane];
        a0 += bflo(v.x); a1 += bfhi(v.x); a2 += bflo(v.y); a3 += bfhi(v.y);
    }

    float di = dis[nodec];
    float4 bb = ((const float4*)b1)[lane];
    srow[grp][4 * lane]     = fmaxf(di * a0 + bb.x, 0.f);
    srow[grp][4 * lane + 1] = fmaxf(di * a1 + bb.y, 0.f);
    srow[grp][4 * lane + 2] = fmaxf(di * a2 + bb.z, 0.f);
    srow[grp][4 * lane + 3] = fmaxf(di * a3 + bb.w, 0.f);
    __syncthreads();   // covers sW2 staging AND srow writes

    const float4* sW2v = (const float4*)sW2;
    float o0 = 0.f, o1 = 0.f, o2 = 0.f, o3 = 0.f;
#pragma unroll
    for (int k = 0; k < H; k++) {
        float rv = srow[grp][k];           // broadcast within group
        float4 w = sW2v[k * 8 + lane];
        o0 += rv * w.x; o1 += rv * w.y; o2 += rv * w.z; o3 += rv * w.w;
    }
    uint2 yv = ((const uint2*)y2)[(size_t)nodec * 8 + lane];
    o0 = di * (o0 + bflo(yv.x));
    o1 = di * (o1 + bfhi(yv.x));
    o2 = di * (o2 + bflo(yv.y));
    o3 = di * (o3 + bfhi(yv.y));

    if (node < N) {
        uint2 p;
        p.x = packbf2(o0, o1);
        p.y = packbf2(o2, o3);
        ((uint2*)g_out)[(size_t)node * 8 + lane] = p;
    }
}

// ---- fused gather #2 + prediction head, 8 lanes/node ----
__global__ __launch_bounds__(256) void agg_final(
    const int* __restrict__ rowptr, const int* __restrict__ rowcnt,
    const int* __restrict__ sorted_src,
    const __hip_bfloat16* __restrict__ g_in, const float* __restrict__ hp,
    const float* __restrict__ dis, const float* __restrict__ b2,
    const float* __restrict__ Wp, float* __restrict__ out, int N)
{
    int gid = blockIdx.x * blockDim.x + threadIdx.x;
    int node = gid >> 3;
    if (node >= N) return;
    int lane = gid & 7;

    const uint2* gv2 = (const uint2*)g_in;
    uint2 sv = gv2[(size_t)node * 8 + lane];
    float a0 = bflo(sv.x), a1 = bfhi(sv.x), a2 = bflo(sv.y), a3 = bfhi(sv.y);

    int start = rowptr[node];
    int end = start + rowcnt[node];
    int i = start;
    for (; i + 7 < end; i += 8) {
        int s0 = sorted_src[i],     s1 = sorted_src[i + 1];
        int s2 = sorted_src[i + 2], s3 = sorted_src[i + 3];
        int s4 = sorted_src[i + 4], s5 = sorted_src[i + 5];
        int s6 = sorted_src[i + 6], s7 = sorted_src[i + 7];
        uint2 v0 = gv2[(size_t)s0 * 8 + lane], v1 = gv2[(size_t)s1 * 8 + lane];
        uint2 v2 = gv2[(size_t)s2 * 8 + lane], v3 = gv2[(size_t)s3 * 8 + lane];
        uint2 v4 = gv2[(size_t)s4 * 8 + lane], v5 = gv2[(size_t)s5 * 8 + lane];
        uint2 v6 = gv2[(size_t)s6 * 8 + lane], v7 = gv2[(size_t)s7 * 8 + lane];
        a0 += bflo(v0.x) + bflo(v1.x) + bflo(v2.x) + bflo(v3.x)
            + bflo(v4.x) + bflo(v5.x) + bflo(v6.x) + bflo(v7.x);
        a1 += bfhi(v0.x) + bfhi(v1.x) + bfhi(v2.x) + bfhi(v3.x)
            + bfhi(v4.x) + bfhi(v5.x) + bfhi(v6.x) + bfhi(v7.x);
        a2 += bflo(v0.y) + bflo(v1.y) + bflo(v2.y) + bflo(v3.y)
            + bflo(v4.y) + bflo(v5.y) + bflo(v6.y) + bflo(v7.y);
        a3 += bfhi(v0.y) + bfhi(v1.y) + bfhi(v2.y) + bfhi(v3.y)
            + bfhi(v4.y) + bfhi(v5.y) + bfhi(v6.y) + bfhi(v7.y);
    }
    for (; i < end; i++) {
        uint2 v = gv2[(size_t)sorted_src[i] * 8 + lane];
        a0 += bflo(v.x); a1 += bfhi(v.x); a2 += bflo(v.y); a3 += bfhi(v.y);
    }

    float di = dis[node];
    float4 b2v = ((const float4*)b2)[lane];
    float4 wp  = ((const float4*)Wp)[lane];
    float v = fmaxf(di * a0 + b2v.x, 0.f) * wp.x
            + fmaxf(di * a1 + b2v.y, 0.f) * wp.y
            + fmaxf(di * a2 + b2v.z, 0.f) * wp.z
            + fmaxf(di * a3 + b2v.w, 0.f) * wp.w;
#pragma unroll
    for (int off = 4; off > 0; off >>= 1) v += __shfl_down(v, off, 8);
    if (lane == 0) out[node] = fmaxf(v + hp[node], 0.f);
}

extern "C" void kernel_launch(void* const* d_in, const int* in_sizes, int n_in,
                              void* d_out, int out_size, void* d_ws, size_t ws_size,
                              hipStream_t stream) {
    const float* x  = (const float*)d_in[0];
    const int*   ei = (const int*)d_in[1];
    const float* We = (const float*)d_in[2];
    const float* be = (const float*)d_in[3];
    const float* W1 = (const float*)d_in[4];
    const float* b1 = (const float*)d_in[5];
    const float* W2 = (const float*)d_in[6];
    const float* b2 = (const float*)d_in[7];
    const float* Wp = (const float*)d_in[8];
    const float* bp = (const float*)d_in[9];
    float* out = (float*)d_out;

    const int N = in_sizes[0] / NF;
    const int E = in_sizes[1] / 2;
    const int* src = ei;
    const int* dst = ei + E;
    const int NB = (N + 255) >> BSH;                // 391
    const int nchunk = (E + BCHUNK - 1) / BCHUNK;   // 391

    // workspace layout
    size_t Np  = ((size_t)N + 127) & ~(size_t)127;
    size_t NHp = ((size_t)N * H + 127) & ~(size_t)127;
    float* ws  = (float*)d_ws;
    float* dis = ws;                      // Np
    float* hp  = dis + Np;                // Np
    __hip_bfloat16* g1 = (__hip_bfloat16*)(hp + Np);   // NHp bf16
    __hip_bfloat16* g2 = g1 + NHp;                     // NHp bf16
    __hip_bfloat16* y2 = g2 + NHp;                     // NHp bf16
    int* cursor     = (int*)(y2 + NHp);   // 512
    int* rowptr     = cursor + 512;       // Np
    int* rowcnt     = rowptr + Np;        // Np
    int* binned     = rowcnt + Np;        // NB*CAP
    int* sorted_src = binned + (size_t)NB * CAP;  // NB*CAP

    init_cur<<<2, 256, 0, stream>>>(cursor, NB);
    bin_edges<<<nchunk, 512, 0, stream>>>(src, dst, cursor, binned, E, NB);
    bucket_csr<<<NB, 1024, 0, stream>>>(cursor, binned, rowptr, rowcnt, sorted_src, dis, N);

    int ngrp = (N + 7) >> 3;
    int eg = ngrp < 1536 ? ngrp : 1536;
    embed_g1<<<eg, 256, 0, stream>>>(x, We, be, W1, W2, Wp, bp, dis, g1, y2, hp, N);
    agg_mid<<<(N + 31) / 32, 256, 0, stream>>>(rowptr, rowcnt, sorted_src, g1, y2, dis, W2, b1, g2, N);
    agg_final<<<((size_t)N * 8 + 255) / 256, 256, 0, stream>>>(rowptr, rowcnt, sorted_src, g2, hp, dis, b2, Wp, out, N);
}